// Round 9
// baseline (2087.167 us; speedup 1.0000x reference)
//
#include <hip/hip_runtime.h>
#include <math.h>

#define ALIGN16 __attribute__((aligned(16)))

__device__ __forceinline__ float rcpf_(float x){ return __builtin_amdgcn_rcpf(x); }
__device__ __forceinline__ float tanh_e(float x){
  float t = __expf(2.0f*x);
  return (t - 1.0f) * rcpf_(t + 1.0f);
}
__device__ __forceinline__ float sigm(float x){
  return rcpf_(1.0f + __expf(-x));
}

// 256 threads (4 waves, 1 wave/SIMD) per batch element; 256 blocks, 1/CU.
// (256,1) is the only config granting the full 512-reg unified budget (R8:
// 252 VGPR, zero spills). R8 was latency-bound (VALUBusy 25%, 10.4k cy/step):
// z-phase LDS loads couldn't pipeline with no free arch regs. R9:
//  - P[64] -> LDS s_P[256][65] (conflict-free rows)  => ~64 regs freed
//  - z-loop explicitly double-buffered (8 groups of 8 float4, 1 group ahead)
//  - LSTM state (h,c) register-resident per lane, redundantly updated by all
//    4 waves; A-phase gathers via __shfl; wave0 publishes s_h/s_xenc.
//    => serial tid<64 phase gone, 3 barriers/step (A|C|z).
__global__ __launch_bounds__(256, 1)
void darnn_fused(const float* __restrict__ gin,   // [256][64][256]
                 const float* __restrict__ eKg,   // [256][256]
                 const float* __restrict__ eRg,   // [64][256]
                 const float* __restrict__ ebg,   // [256]
                 const float* __restrict__ dKg,   // [64][256]
                 const float* __restrict__ dRg,   // [64][256]
                 const float* __restrict__ dbg,   // [256]
                 const float* __restrict__ aeW,   // [192][64]
                 const float* __restrict__ aeb,   // [64]
                 const float* __restrict__ aev,   // [64]
                 const float* __restrict__ adW,   // [192][64]
                 const float* __restrict__ adb,   // [64]
                 const float* __restrict__ adv,   // [64]
                 const float* __restrict__ fcW,   // [65][64]
                 const float* __restrict__ fcb,   // [64]
                 const float* __restrict__ fcfW,  // [128][256]
                 const float* __restrict__ fcfb,  // [256]
                 float* __restrict__ out)         // [256][256]
{
  __shared__ ALIGN16 float s_w[4160];      // We_x -> Wd_x -> fcW(65x64)
  __shared__ ALIGN16 float s_P[256*65];    // exp(2*x_proj), row stride 65
  __shared__ ALIGN16 float s_xenc[64*68];  // x_encoded
  __shared__ ALIGN16 float s_ag[256];      // activated gates
  __shared__ ALIGN16 float s_xtld[256];    // unnormalized x_tilde
  __shared__ ALIGN16 float s_hs[64];       // E_u = exp(2*preact_u)
  __shared__ ALIGN16 float s_pe[64];       // decoder unnorm softmax
  __shared__ ALIGN16 float s_redB[4];      // per-wave softmax partials
  __shared__ ALIGN16 float s_ctx[64];
  __shared__ ALIGN16 float s_yprev[64];
  __shared__ ALIGN16 float s_h[64];        // h (enc) / d (dec), wave0-published
  __shared__ ALIGN16 float s_aev[64];

  const int tid  = threadIdx.x;   // 0..255 = f = k
  const int lane = tid & 63;
  const int wv   = tid >> 6;      // 0..3
  const int u4   = tid >> 2;      // 0..63
  const int g4   = tid & 3;
  const int b    = blockIdx.x;
  const float* inb = gin + (size_t)b * (64*256);

  // ================= encoder prologue =================
  for (int i = tid; i < 4096; i += 256) s_w[i] = aeW[8192 + i];   // We_x
  if (tid < 64) { s_aev[tid] = aev[tid]; s_h[tid] = 0.f; }
  __syncthreads();

  // x_proj -> s_P[tid][u] = exp(2*xp_u)  (step-invariant)
  {
    float xp[64];
#pragma unroll
    for (int i = 0; i < 64; ++i) xp[i] = 0.f;
    for (int t = 0; t < 64; ++t) {
      float xv = inb[t*256 + tid];
#pragma unroll
      for (int q = 0; q < 16; ++q) {
        float4 w = *(const float4*)&s_w[t*64 + q*4];
        xp[q*4+0] = fmaf(xv, w.x, xp[q*4+0]);
        xp[q*4+1] = fmaf(xv, w.y, xp[q*4+1]);
        xp[q*4+2] = fmaf(xv, w.z, xp[q*4+2]);
        xp[q*4+3] = fmaf(xv, w.w, xp[q*4+3]);
      }
    }
#pragma unroll
    for (int i = 0; i < 64; ++i) s_P[tid*65 + i] = __expf(2.0f*xp[i]);
  }
  float vsum = 0.f;
#pragma unroll
  for (int q = 0; q < 16; ++q) {
    float4 v = *(const float4*)&s_aev[q*4];
    vsum += (v.x + v.y) + (v.z + v.w);
  }

  float eKr[256];
#pragma unroll
  for (int q = 0; q < 256; ++q) eKr[q] = eKg[q*256 + tid];
  float eRr[64];
#pragma unroll
  for (int j = 0; j < 64; ++j) eRr[j] = eRg[j*256 + tid];
  float wh[16], wsr[16];
#pragma unroll
  for (int jj = 0; jj < 16; ++jj) {
    wh[jj]  = aeW[(g4*16 + jj)*64 + u4];
    wsr[jj] = aeW[(64 + g4*16 + jj)*64 + u4];
  }
  const float aeb_u = aeb[u4];
  const float eb_k  = ebg[tid];
  float h_j = 0.f, c_j = 0.f;   // per-wave redundant state, j = lane
  __syncthreads();

  // ================= encoder loop (3 barriers/step) =================
  for (int t = 0; t < 64; ++t) {
    if (t > 0) {  // redundant LSTM update from z(t-1)
      float gi = s_ag[lane], gf = s_ag[64+lane], gg = s_ag[128+lane], go = s_ag[192+lane];
      c_j = fmaf(gf, c_j, gi*gg);
      h_j = go * tanh_e(c_j);
      if (wv == 0) { s_h[lane] = h_j; s_xenc[(t-1)*68 + lane] = h_j; }
    }
    float xtv = inb[t*256 + tid];
    // A: E_u via register state + shfl
    float p0 = 0.f, p1 = 0.f;
#pragma unroll
    for (int jj = 0; jj < 16; ++jj) {
      float hh = __shfl(h_j, g4*16 + jj);
      float cc = __shfl(c_j, g4*16 + jj);
      p0 = fmaf(hh, wh[jj], p0);
      p1 = fmaf(cc, wsr[jj], p1);
    }
    float p = p0 + p1;
    p += __shfl_xor(p, 1); p += __shfl_xor(p, 2);
    float E = __expf(2.0f*(p + aeb_u));
    if (g4 == 0) s_hs[u4] = E;
    __syncthreads();  // b1

    // C: sc = vsum - 2*sum_u v_u*rcp(E_u*P_u+1); softmax w/o max-sub
    float sA = 0.f, sB = 0.f, sC = 0.f, sD = 0.f;
#pragma unroll
    for (int q = 0; q < 16; ++q) {
      float4 Ev = *(const float4*)&s_hs[q*4];
      float4 vv = *(const float4*)&s_aev[q*4];
      float4 Pv = *(const float4*)&s_P[tid*65 + q*4];
      sA = fmaf(vv.x, rcpf_(fmaf(Ev.x, Pv.x, 1.f)), sA);
      sB = fmaf(vv.y, rcpf_(fmaf(Ev.y, Pv.y, 1.f)), sB);
      sC = fmaf(vv.z, rcpf_(fmaf(Ev.z, Pv.z, 1.f)), sC);
      sD = fmaf(vv.w, rcpf_(fmaf(Ev.w, Pv.w, 1.f)), sD);
    }
    float sc = fmaf(-2.f, (sA+sB)+(sC+sD), vsum);
    float pe = __expf(sc);
    float ws = pe;
    ws += __shfl_xor(ws,1);  ws += __shfl_xor(ws,2);  ws += __shfl_xor(ws,4);
    ws += __shfl_xor(ws,8);  ws += __shfl_xor(ws,16); ws += __shfl_xor(ws,32);
    if (lane == 0) s_redB[wv] = ws;
    s_xtld[tid] = pe * xtv;
    __syncthreads();  // b2

    // z: (xtld.eK)*invS + h.eR + eb  — double-buffered group loads
    float4 r = *(const float4*)&s_redB[0];
    float invS = rcpf_((r.x + r.y) + (r.z + r.w));
    float a0 = 0.f, a1 = 0.f, a2 = 0.f, a3 = 0.f;
    {
      float4 xa[8], xb[8];
#pragma unroll
      for (int i = 0; i < 8; ++i) xa[i] = *(const float4*)&s_xtld[i*4];
#pragma unroll
      for (int g = 0; g < 8; ++g) {
        if ((g & 1) == 0) {
          if (g < 7) {
#pragma unroll
            for (int i = 0; i < 8; ++i) xb[i] = *(const float4*)&s_xtld[(g+1)*32 + i*4];
          }
#pragma unroll
          for (int i = 0; i < 8; ++i) {
            a0 = fmaf(xa[i].x, eKr[g*32 + i*4+0], a0);
            a1 = fmaf(xa[i].y, eKr[g*32 + i*4+1], a1);
            a2 = fmaf(xa[i].z, eKr[g*32 + i*4+2], a2);
            a3 = fmaf(xa[i].w, eKr[g*32 + i*4+3], a3);
          }
        } else {
          if (g < 7) {
#pragma unroll
            for (int i = 0; i < 8; ++i) xa[i] = *(const float4*)&s_xtld[(g+1)*32 + i*4];
          }
#pragma unroll
          for (int i = 0; i < 8; ++i) {
            a0 = fmaf(xb[i].x, eKr[g*32 + i*4+0], a0);
            a1 = fmaf(xb[i].y, eKr[g*32 + i*4+1], a1);
            a2 = fmaf(xb[i].z, eKr[g*32 + i*4+2], a2);
            a3 = fmaf(xb[i].w, eKr[g*32 + i*4+3], a3);
          }
        }
      }
    }
    float h0 = 0.f, h1 = 0.f;
#pragma unroll
    for (int q = 0; q < 16; ++q) {
      float4 h4 = *(const float4*)&s_h[q*4];
      h0 = fmaf(h4.x, eRr[q*4+0], h0); h1 = fmaf(h4.y, eRr[q*4+1], h1);
      h0 = fmaf(h4.z, eRr[q*4+2], h0); h1 = fmaf(h4.w, eRr[q*4+3], h1);
    }
    float v = fmaf((a0+a1)+(a2+a3), invS, (h0+h1) + eb_k);
    float a = (wv == 2) ? tanh_e(v) : sigm(v);
    s_ag[tid] = a;
    __syncthreads();  // b3
  }
  // final encoder update -> xenc row 63
  {
    float gi = s_ag[lane], gf = s_ag[64+lane], gg = s_ag[128+lane], go = s_ag[192+lane];
    c_j = fmaf(gf, c_j, gi*gg);
    h_j = go * tanh_e(c_j);
    if (wv == 0) s_xenc[63*68 + lane] = h_j;
  }

  // ================= decoder prologue =================
  h_j = 0.f; c_j = 0.f;
  for (int i = tid; i < 4096; i += 256) s_w[i] = adW[8192 + i];   // Wd_x
  if (tid < 64) { s_h[tid] = 0.f; s_yprev[tid] = inb[tid*256 + 255]; }
  __syncthreads();  // d1 (also orders xenc row 63)

  // pd_[i] = exp(2*xe_proj[t'=u4][g4*16+i])  (step-invariant)
  float pd_[16];
  {
    float xe[16];
#pragma unroll
    for (int i = 0; i < 16; ++i) xe[i] = 0.f;
    for (int e = 0; e < 64; ++e) {
      float xv = s_xenc[u4*68 + e];
#pragma unroll
      for (int q = 0; q < 4; ++q) {
        float4 w = *(const float4*)&s_w[e*64 + g4*16 + q*4];
        xe[q*4+0] = fmaf(xv, w.x, xe[q*4+0]);
        xe[q*4+1] = fmaf(xv, w.y, xe[q*4+1]);
        xe[q*4+2] = fmaf(xv, w.z, xe[q*4+2]);
        xe[q*4+3] = fmaf(xv, w.w, xe[q*4+3]);
      }
    }
#pragma unroll
    for (int i = 0; i < 16; ++i) pd_[i] = __expf(2.0f*xe[i]);
  }
  float dKr[64];
#pragma unroll
  for (int j = 0; j < 64; ++j) dKr[j] = dKg[j*256 + tid];
  __syncthreads();  // d2: Wd_x dead
  for (int i = tid; i < 4160; i += 256) s_w[i] = fcW[i];
  __syncthreads();  // d3

  // macc[e] = (fcW_ctx @ dK)[e][k];  m2k, mbk folds
  float m2k = 0.f, mbk = dbg[tid];
  float macc[64];
#pragma unroll
  for (int e = 0; e < 64; ++e) {
    float c0 = 0.f, c1 = 0.f;
#pragma unroll
    for (int q = 0; q < 16; ++q) {
      float4 w = *(const float4*)&s_w[e*64 + q*4];
      c0 = fmaf(w.x, dKr[q*4+0], c0); c1 = fmaf(w.y, dKr[q*4+1], c1);
      c0 = fmaf(w.z, dKr[q*4+2], c0); c1 = fmaf(w.w, dKr[q*4+3], c1);
    }
    macc[e] = c0 + c1;
  }
#pragma unroll
  for (int q = 0; q < 16; ++q) {
    float4 w = *(const float4*)&s_w[4096 + q*4];   // fcW row 64
    m2k = fmaf(w.x, dKr[q*4+0], m2k); m2k = fmaf(w.y, dKr[q*4+1], m2k);
    m2k = fmaf(w.z, dKr[q*4+2], m2k); m2k = fmaf(w.w, dKr[q*4+3], m2k);
    mbk = fmaf(fcb[q*4+0], dKr[q*4+0], mbk); mbk = fmaf(fcb[q*4+1], dKr[q*4+1], mbk);
    mbk = fmaf(fcb[q*4+2], dKr[q*4+2], mbk); mbk = fmaf(fcb[q*4+3], dKr[q*4+3], mbk);
  }
  // XMr[t] = sum_e xenc[t][e]*macc[e]
  float XMr[64];
#pragma unroll
  for (int t = 0; t < 64; ++t) {
    float c0 = 0.f, c1 = 0.f;
#pragma unroll
    for (int q = 0; q < 16; ++q) {
      float4 xv = *(const float4*)&s_xenc[t*68 + q*4];
      c0 = fmaf(xv.x, macc[q*4+0], c0); c1 = fmaf(xv.y, macc[q*4+1], c1);
      c0 = fmaf(xv.z, macc[q*4+2], c0); c1 = fmaf(xv.w, macc[q*4+3], c1);
    }
    XMr[t] = c0 + c1;
  }
  float dRr[64];
#pragma unroll
  for (int j = 0; j < 64; ++j) dRr[j] = dRg[j*256 + tid];
  float wdd[16], wdc[16], advr[16];
#pragma unroll
  for (int jj = 0; jj < 16; ++jj) {
    wdd[jj]  = adW[(g4*16 + jj)*64 + u4];
    wdc[jj]  = adW[(64 + g4*16 + jj)*64 + u4];
    advr[jj] = adv[g4*16 + jj];
  }
  float vsumd = 0.f;
#pragma unroll
  for (int i = 0; i < 16; ++i) vsumd += advr[i];
  vsumd += __shfl_xor(vsumd, 1); vsumd += __shfl_xor(vsumd, 2);
  const float adb_u = adb[u4];

  // ================= decoder loop (3 barriers/step) =================
  for (int t = 0; t < 64; ++t) {
    if (t > 0) {  // redundant update
      float gi = s_ag[lane], gf = s_ag[64+lane], gg = s_ag[128+lane], go = s_ag[192+lane];
      c_j = fmaf(gf, c_j, gi*gg);
      h_j = go * tanh_e(c_j);
      if (wv == 0) s_h[lane] = h_j;
    }
    // A
    float p0 = 0.f, p1 = 0.f;
#pragma unroll
    for (int jj = 0; jj < 16; ++jj) {
      float hh = __shfl(h_j, g4*16 + jj);
      float cc = __shfl(c_j, g4*16 + jj);
      p0 = fmaf(hh, wdd[jj], p0);
      p1 = fmaf(cc, wdc[jj], p1);
    }
    float p = p0 + p1;
    p += __shfl_xor(p, 1); p += __shfl_xor(p, 2);
    float E = __expf(2.0f*(p + adb_u));
    if (g4 == 0) s_hs[u4] = E;
    __syncthreads();  // b1

    // C: t'=u4, u-slice g4*16..+16
    float sA = 0.f, sB = 0.f;
#pragma unroll
    for (int q = 0; q < 4; ++q) {
      float4 Ev = *(const float4*)&s_hs[g4*16 + q*4];
      sA = fmaf(advr[q*4+0], rcpf_(fmaf(Ev.x, pd_[q*4+0], 1.f)), sA);
      sB = fmaf(advr[q*4+1], rcpf_(fmaf(Ev.y, pd_[q*4+1], 1.f)), sB);
      sA = fmaf(advr[q*4+2], rcpf_(fmaf(Ev.z, pd_[q*4+2], 1.f)), sA);
      sB = fmaf(advr[q*4+3], rcpf_(fmaf(Ev.w, pd_[q*4+3], 1.f)), sB);
    }
    float sacc = sA + sB;
    sacc += __shfl_xor(sacc, 1); sacc += __shfl_xor(sacc, 2);
    float sc = fmaf(-2.f, sacc, vsumd);
    float pe = __expf(sc);
    if (g4 == 0) s_pe[u4] = pe;
    float ws = pe;   // xor{4..32} sums the wave's 16 distinct t' once each
    ws += __shfl_xor(ws,4); ws += __shfl_xor(ws,8);
    ws += __shfl_xor(ws,16); ws += __shfl_xor(ws,32);
    if (lane == 0) s_redB[wv] = ws;
    __syncthreads();  // b2

    // z: invS*(pe.XMr) + d.dRr + y*m2k + mbk
    float4 r = *(const float4*)&s_redB[0];
    float invS = rcpf_((r.x + r.y) + (r.z + r.w));
    float q0 = 0.f, q1 = 0.f;
#pragma unroll
    for (int q = 0; q < 16; ++q) {
      float4 pv = *(const float4*)&s_pe[q*4];
      q0 = fmaf(pv.x, XMr[q*4+0], q0); q1 = fmaf(pv.y, XMr[q*4+1], q1);
      q0 = fmaf(pv.z, XMr[q*4+2], q0); q1 = fmaf(pv.w, XMr[q*4+3], q1);
    }
    float r0 = 0.f, r1 = 0.f;
#pragma unroll
    for (int q = 0; q < 16; ++q) {
      float4 h4 = *(const float4*)&s_h[q*4];
      r0 = fmaf(h4.x, dRr[q*4+0], r0); r1 = fmaf(h4.y, dRr[q*4+1], r1);
      r0 = fmaf(h4.z, dRr[q*4+2], r0); r1 = fmaf(h4.w, dRr[q*4+3], r1);
    }
    float v = fmaf(q0+q1, invS, fmaf(s_yprev[t], m2k, (r0+r1) + mbk));
    float a = (wv == 2) ? tanh_e(v) : sigm(v);
    s_ag[tid] = a;
    __syncthreads();  // b3
  }
  // final decoder update -> d_n published
  {
    float gi = s_ag[lane], gf = s_ag[64+lane], gg = s_ag[128+lane], go = s_ag[192+lane];
    c_j = fmaf(gf, c_j, gi*gg);
    h_j = go * tanh_e(c_j);
    if (wv == 0) s_h[lane] = h_j;
  }
  __syncthreads();

  // final context from last step's pe/S
  {
    float4 r = *(const float4*)&s_redB[0];
    float invS = rcpf_((r.x + r.y) + (r.z + r.w));
    float pc = 0.f;
#pragma unroll
    for (int q = 0; q < 16; ++q)
      pc = fmaf(s_pe[g4*16 + q], s_xenc[(g4*16 + q)*68 + u4], pc);
    pc += __shfl_xor(pc, 1); pc += __shfl_xor(pc, 2);
    if (g4 == 0) s_ctx[u4] = pc * invS;
  }
  __syncthreads();

  // epilogue: out = [d_n, ctx] @ fcfW + fcfb
  {
    float a0 = fcfb[tid], a1 = 0.f, a2 = 0.f, a3 = 0.f;
#pragma unroll
    for (int q = 0; q < 16; ++q) {
      float4 h4 = *(const float4*)&s_h[q*4];
      a0 = fmaf(h4.x, fcfW[(q*4+0)*256 + tid], a0);
      a1 = fmaf(h4.y, fcfW[(q*4+1)*256 + tid], a1);
      a2 = fmaf(h4.z, fcfW[(q*4+2)*256 + tid], a2);
      a3 = fmaf(h4.w, fcfW[(q*4+3)*256 + tid], a3);
      float4 c4 = *(const float4*)&s_ctx[q*4];
      a0 = fmaf(c4.x, fcfW[(64 + q*4+0)*256 + tid], a0);
      a1 = fmaf(c4.y, fcfW[(64 + q*4+1)*256 + tid], a1);
      a2 = fmaf(c4.z, fcfW[(64 + q*4+2)*256 + tid], a2);
      a3 = fmaf(c4.w, fcfW[(64 + q*4+3)*256 + tid], a3);
    }
    out[b*256 + tid] = (a0 + a1) + (a2 + a3);
  }
}

extern "C" void kernel_launch(void* const* d_in, const int* in_sizes, int n_in,
                              void* d_out, int out_size, void* d_ws, size_t ws_size,
                              hipStream_t stream) {
  const float* gin  = (const float*)d_in[0];
  const float* eK   = (const float*)d_in[1];
  const float* eR   = (const float*)d_in[2];
  const float* eb   = (const float*)d_in[3];
  const float* dK   = (const float*)d_in[4];
  const float* dR   = (const float*)d_in[5];
  const float* db   = (const float*)d_in[6];
  const float* aeW  = (const float*)d_in[7];
  const float* aeb  = (const float*)d_in[8];
  const float* aev  = (const float*)d_in[9];
  // d_in[10] attn_e_vb, d_in[14] attn_d_vb: constant shifts, cancel in softmax
  const float* adW  = (const float*)d_in[11];
  const float* adb  = (const float*)d_in[12];
  const float* adv  = (const float*)d_in[13];
  const float* fcW  = (const float*)d_in[15];
  const float* fcb  = (const float*)d_in[16];
  const float* fcfW = (const float*)d_in[17];
  const float* fcfb = (const float*)d_in[18];
  float* out = (float*)d_out;

  const int B = in_sizes[0] / (64*256);
  hipLaunchKernelGGL(darnn_fused, dim3(B), dim3(256), 0, stream,
                     gin, eK, eR, eb, dK, dR, db, aeW, aeb, aev,
                     adW, adb, adv, fcW, fcb, fcfW, fcfb, out);
}

// Round 10
// 531.780 us; speedup vs baseline: 3.9249x; 3.9249x over previous
//
#include <hip/hip_runtime.h>
#include <math.h>

#define ALIGN16 __attribute__((aligned(16)))

__device__ __forceinline__ float rcpf_(float x){ return __builtin_amdgcn_rcpf(x); }
__device__ __forceinline__ float tanh_e(float x){
  float t = __expf(2.0f*x);
  return (t - 1.0f) * rcpf_(t + 1.0f);
}
__device__ __forceinline__ float sigm(float x){
  return rcpf_(1.0f + __expf(-x));
}

// 256 threads (4 waves, 1 wave/SIMD) per batch element; 256 blocks, 1/CU.
// R8 (252 VGPR, zero spills, 553us) was latency-bound: z-phase's 64 broadcast
// LDS loads couldn't pipeline (no free regs). R9 proved that ADDING buffers
// on top spills catastrophically. R10 = R8 + only pressure-REDUCING changes:
//  - P[64] -> LDS transposed s_P[64][256]: reads s_P[u*256+tid] are
//    lane-consecutive (conflict-free); frees ~64 regs as a prefetch pool.
//  - h.eR (enc) / d.dR (dec) hoisted into the A-phase (depends only on s_h,
//    ready before b1): fills the thin A phase, shortens the z critical path.
//  - everything else identical to R8 (serial update, 4 barriers/step).
__global__ __launch_bounds__(256, 1)
void darnn_fused(const float* __restrict__ gin,   // [256][64][256]
                 const float* __restrict__ eKg,   // [256][256]
                 const float* __restrict__ eRg,   // [64][256]
                 const float* __restrict__ ebg,   // [256]
                 const float* __restrict__ dKg,   // [64][256]
                 const float* __restrict__ dRg,   // [64][256]
                 const float* __restrict__ dbg,   // [256]
                 const float* __restrict__ aeW,   // [192][64]
                 const float* __restrict__ aeb,   // [64]
                 const float* __restrict__ aev,   // [64]
                 const float* __restrict__ adW,   // [192][64]
                 const float* __restrict__ adb,   // [64]
                 const float* __restrict__ adv,   // [64]
                 const float* __restrict__ fcW,   // [65][64]
                 const float* __restrict__ fcb,   // [64]
                 const float* __restrict__ fcfW,  // [128][256]
                 const float* __restrict__ fcfb,  // [256]
                 float* __restrict__ out)         // [256][256]
{
  __shared__ ALIGN16 float s_w[4160];      // We_x -> Wd_x -> fcW(65x64)
  __shared__ ALIGN16 float s_P[64*256];    // exp(2*x_proj) TRANSPOSED [u][f]
  __shared__ ALIGN16 float s_xenc[64*68];  // x_encoded
  __shared__ ALIGN16 float s_ag[256];      // activated gates
  __shared__ ALIGN16 float s_xtld[256];    // unnormalized x_tilde
  __shared__ ALIGN16 float s_hs[64];       // E_u = exp(2*preact_u)
  __shared__ ALIGN16 float s_pe[64];       // decoder unnorm softmax
  __shared__ ALIGN16 float s_redB[4];      // per-wave softmax partials
  __shared__ ALIGN16 float s_ctx[64];
  __shared__ ALIGN16 float s_yprev[64];
  __shared__ ALIGN16 float s_h[64];        // h (enc) / d (dec)
  __shared__ ALIGN16 float s_c[64];        // c (enc) / c' (dec)
  __shared__ ALIGN16 float s_aev[64];

  const int tid  = threadIdx.x;   // 0..255 = f = k
  const int lane = tid & 63;
  const int wv   = tid >> 6;      // 0..3
  const int u4   = tid >> 2;      // 0..63
  const int g4   = tid & 3;
  const int b    = blockIdx.x;
  const float* inb = gin + (size_t)b * (64*256);

  // ================= encoder prologue =================
  for (int i = tid; i < 4096; i += 256) s_w[i] = aeW[8192 + i];   // We_x
  if (tid < 64) { s_aev[tid] = aev[tid]; s_h[tid] = 0.f; s_c[tid] = 0.f; }
  __syncthreads();

  // x_proj -> s_P[u][f] = exp(2*xp) (transposed, step-invariant)
  {
    float xp[64];
#pragma unroll
    for (int i = 0; i < 64; ++i) xp[i] = 0.f;
    for (int t = 0; t < 64; ++t) {
      float xv = inb[t*256 + tid];
#pragma unroll
      for (int q = 0; q < 16; ++q) {
        float4 w = *(const float4*)&s_w[t*64 + q*4];
        xp[q*4+0] = fmaf(xv, w.x, xp[q*4+0]);
        xp[q*4+1] = fmaf(xv, w.y, xp[q*4+1]);
        xp[q*4+2] = fmaf(xv, w.z, xp[q*4+2]);
        xp[q*4+3] = fmaf(xv, w.w, xp[q*4+3]);
      }
    }
#pragma unroll
    for (int i = 0; i < 64; ++i) s_P[i*256 + tid] = __expf(2.0f*xp[i]);
  }
  float vsum = 0.f;
#pragma unroll
  for (int q = 0; q < 16; ++q) {
    float4 v = *(const float4*)&s_aev[q*4];
    vsum += (v.x + v.y) + (v.z + v.w);
  }

  // register-resident weights (unified VGPR+AGPR budget at 1 wave/EU)
  float eKr[256];
#pragma unroll
  for (int q = 0; q < 256; ++q) eKr[q] = eKg[q*256 + tid];
  float eRr[64];
#pragma unroll
  for (int j = 0; j < 64; ++j) eRr[j] = eRg[j*256 + tid];
  float wh[16], wsr[16];
#pragma unroll
  for (int jj = 0; jj < 16; ++jj) {
    wh[jj]  = aeW[(g4*16 + jj)*64 + u4];        // We_h[j][u4]
    wsr[jj] = aeW[(64 + g4*16 + jj)*64 + u4];   // We_s[j][u4]
  }
  const float aeb_u = aeb[u4];
  const float eb_k  = ebg[tid];
  __syncthreads();   // s_P visible before first C-phase

  // ================= encoder loop (4 barriers/step) =================
  for (int t = 0; t < 64; ++t) {
    float xtv = inb[t*256 + tid];
    // A: E_u = exp(2*(h@We_h + c@We_s + b)[u])  +  hoisted ph = h.eR
    float p0 = 0.f, p1 = 0.f;
#pragma unroll
    for (int q = 0; q < 4; ++q) {
      float4 h4 = *(const float4*)&s_h[g4*16 + q*4];
      float4 c4 = *(const float4*)&s_c[g4*16 + q*4];
      p0 = fmaf(h4.x, wh[q*4+0], p0);  p0 = fmaf(h4.y, wh[q*4+1], p0);
      p0 = fmaf(h4.z, wh[q*4+2], p0);  p0 = fmaf(h4.w, wh[q*4+3], p0);
      p1 = fmaf(c4.x, wsr[q*4+0], p1); p1 = fmaf(c4.y, wsr[q*4+1], p1);
      p1 = fmaf(c4.z, wsr[q*4+2], p1); p1 = fmaf(c4.w, wsr[q*4+3], p1);
    }
    float ph0 = 0.f, ph1 = 0.f;   // h . eR (independent of A's reduce)
#pragma unroll
    for (int q = 0; q < 16; ++q) {
      float4 h4 = *(const float4*)&s_h[q*4];
      ph0 = fmaf(h4.x, eRr[q*4+0], ph0); ph1 = fmaf(h4.y, eRr[q*4+1], ph1);
      ph0 = fmaf(h4.z, eRr[q*4+2], ph0); ph1 = fmaf(h4.w, eRr[q*4+3], ph1);
    }
    float p = p0 + p1;
    p += __shfl_xor(p, 1); p += __shfl_xor(p, 2);
    float E = __expf(2.0f*(p + aeb_u));
    if (g4 == 0) s_hs[u4] = E;
    __syncthreads();  // b1

    // C: sc = vsum - 2*sum_u v_u*rcp(E_u*P_u+1); softmax w/o max-sub
    float sA = 0.f, sB = 0.f, sC = 0.f, sD = 0.f;
#pragma unroll
    for (int q = 0; q < 16; ++q) {
      float4 Ev = *(const float4*)&s_hs[q*4];
      float4 vv = *(const float4*)&s_aev[q*4];
      float P0 = s_P[(q*4+0)*256 + tid];
      float P1 = s_P[(q*4+1)*256 + tid];
      float P2 = s_P[(q*4+2)*256 + tid];
      float P3 = s_P[(q*4+3)*256 + tid];
      sA = fmaf(vv.x, rcpf_(fmaf(Ev.x, P0, 1.f)), sA);
      sB = fmaf(vv.y, rcpf_(fmaf(Ev.y, P1, 1.f)), sB);
      sC = fmaf(vv.z, rcpf_(fmaf(Ev.z, P2, 1.f)), sC);
      sD = fmaf(vv.w, rcpf_(fmaf(Ev.w, P3, 1.f)), sD);
    }
    float sc = fmaf(-2.f, (sA+sB)+(sC+sD), vsum);
    float pe = __expf(sc);
    float ws = pe;
    ws += __shfl_xor(ws,1);  ws += __shfl_xor(ws,2);  ws += __shfl_xor(ws,4);
    ws += __shfl_xor(ws,8);  ws += __shfl_xor(ws,16); ws += __shfl_xor(ws,32);
    if (lane == 0) s_redB[wv] = ws;
    s_xtld[tid] = pe * xtv;
    __syncthreads();  // b2

    // z[k=tid] = (xtld . eK)*invS + ph + eb
    float4 r = *(const float4*)&s_redB[0];
    float invS = rcpf_((r.x + r.y) + (r.z + r.w));
    float a0 = 0.f, a1 = 0.f, a2 = 0.f, a3 = 0.f;
#pragma unroll
    for (int q = 0; q < 64; ++q) {
      float4 x4 = *(const float4*)&s_xtld[q*4];
      a0 = fmaf(x4.x, eKr[q*4+0], a0);
      a1 = fmaf(x4.y, eKr[q*4+1], a1);
      a2 = fmaf(x4.z, eKr[q*4+2], a2);
      a3 = fmaf(x4.w, eKr[q*4+3], a3);
    }
    float v = fmaf((a0+a1)+(a2+a3), invS, (ph0+ph1) + eb_k);
    float a = (wv == 2) ? tanh_e(v) : sigm(v);
    s_ag[tid] = a;
    __syncthreads();  // b3

    if (tid < 64) {
      float gi = s_ag[tid], gf = s_ag[64+tid], gg = s_ag[128+tid], go = s_ag[192+tid];
      float cn = fmaf(gf, s_c[tid], gi*gg);
      float hn = go * tanh_e(cn);
      s_c[tid] = cn; s_h[tid] = hn; s_xenc[t*68 + tid] = hn;
    }
    __syncthreads();  // b4
  }

  // ================= decoder prologue =================
  for (int i = tid; i < 4096; i += 256) s_w[i] = adW[8192 + i];   // Wd_x
  if (tid < 64) { s_h[tid] = 0.f; s_c[tid] = 0.f; s_yprev[tid] = inb[tid*256 + 255]; }
  __syncthreads();  // d1

  // pd_[i] = exp(2*xe_proj[t'=u4][g4*16+i])  (step-invariant)
  float pd_[16];
  {
    float xe[16];
#pragma unroll
    for (int i = 0; i < 16; ++i) xe[i] = 0.f;
    for (int e = 0; e < 64; ++e) {
      float xv = s_xenc[u4*68 + e];
#pragma unroll
      for (int q = 0; q < 4; ++q) {
        float4 w = *(const float4*)&s_w[e*64 + g4*16 + q*4];
        xe[q*4+0] = fmaf(xv, w.x, xe[q*4+0]);
        xe[q*4+1] = fmaf(xv, w.y, xe[q*4+1]);
        xe[q*4+2] = fmaf(xv, w.z, xe[q*4+2]);
        xe[q*4+3] = fmaf(xv, w.w, xe[q*4+3]);
      }
    }
#pragma unroll
    for (int i = 0; i < 16; ++i) pd_[i] = __expf(2.0f*xe[i]);
  }
  float dKr[64];
#pragma unroll
  for (int j = 0; j < 64; ++j) dKr[j] = dKg[j*256 + tid];
  __syncthreads();  // d2: Wd_x dead
  for (int i = tid; i < 4160; i += 256) s_w[i] = fcW[i];
  __syncthreads();  // d3

  // macc[e] = (fcW_ctx @ dK)[e][k];  m2k, mbk folds
  float m2k = 0.f, mbk = dbg[tid];
  float macc[64];
#pragma unroll
  for (int e = 0; e < 64; ++e) {
    float c0 = 0.f, c1 = 0.f;
#pragma unroll
    for (int q = 0; q < 16; ++q) {
      float4 w = *(const float4*)&s_w[e*64 + q*4];
      c0 = fmaf(w.x, dKr[q*4+0], c0); c1 = fmaf(w.y, dKr[q*4+1], c1);
      c0 = fmaf(w.z, dKr[q*4+2], c0); c1 = fmaf(w.w, dKr[q*4+3], c1);
    }
    macc[e] = c0 + c1;
  }
#pragma unroll
  for (int q = 0; q < 16; ++q) {
    float4 w = *(const float4*)&s_w[4096 + q*4];   // fcW row 64
    m2k = fmaf(w.x, dKr[q*4+0], m2k); m2k = fmaf(w.y, dKr[q*4+1], m2k);
    m2k = fmaf(w.z, dKr[q*4+2], m2k); m2k = fmaf(w.w, dKr[q*4+3], m2k);
    mbk = fmaf(fcb[q*4+0], dKr[q*4+0], mbk); mbk = fmaf(fcb[q*4+1], dKr[q*4+1], mbk);
    mbk = fmaf(fcb[q*4+2], dKr[q*4+2], mbk); mbk = fmaf(fcb[q*4+3], dKr[q*4+3], mbk);
  }
  // XMr[t] = sum_e xenc[t][e]*macc[e]
  float XMr[64];
#pragma unroll
  for (int t = 0; t < 64; ++t) {
    float c0 = 0.f, c1 = 0.f;
#pragma unroll
    for (int q = 0; q < 16; ++q) {
      float4 xv = *(const float4*)&s_xenc[t*68 + q*4];
      c0 = fmaf(xv.x, macc[q*4+0], c0); c1 = fmaf(xv.y, macc[q*4+1], c1);
      c0 = fmaf(xv.z, macc[q*4+2], c0); c1 = fmaf(xv.w, macc[q*4+3], c1);
    }
    XMr[t] = c0 + c1;
  }
  float dRr[64];
#pragma unroll
  for (int j = 0; j < 64; ++j) dRr[j] = dRg[j*256 + tid];
  float wdd[16], wdc[16], advr[16];
#pragma unroll
  for (int jj = 0; jj < 16; ++jj) {
    wdd[jj]  = adW[(g4*16 + jj)*64 + u4];
    wdc[jj]  = adW[(64 + g4*16 + jj)*64 + u4];
    advr[jj] = adv[g4*16 + jj];
  }
  float vsumd = 0.f;
#pragma unroll
  for (int i = 0; i < 16; ++i) vsumd += advr[i];
  vsumd += __shfl_xor(vsumd, 1); vsumd += __shfl_xor(vsumd, 2);
  const float adb_u = adb[u4];

  // ================= decoder loop (4 barriers/step) =================
  for (int t = 0; t < 64; ++t) {
    // A  +  hoisted rd = d . dR
    float p0 = 0.f, p1 = 0.f;
#pragma unroll
    for (int q = 0; q < 4; ++q) {
      float4 h4 = *(const float4*)&s_h[g4*16 + q*4];
      float4 c4 = *(const float4*)&s_c[g4*16 + q*4];
      p0 = fmaf(h4.x, wdd[q*4+0], p0);  p0 = fmaf(h4.y, wdd[q*4+1], p0);
      p0 = fmaf(h4.z, wdd[q*4+2], p0);  p0 = fmaf(h4.w, wdd[q*4+3], p0);
      p1 = fmaf(c4.x, wdc[q*4+0], p1);  p1 = fmaf(c4.y, wdc[q*4+1], p1);
      p1 = fmaf(c4.z, wdc[q*4+2], p1);  p1 = fmaf(c4.w, wdc[q*4+3], p1);
    }
    float rd0 = 0.f, rd1 = 0.f;
#pragma unroll
    for (int q = 0; q < 16; ++q) {
      float4 h4 = *(const float4*)&s_h[q*4];
      rd0 = fmaf(h4.x, dRr[q*4+0], rd0); rd1 = fmaf(h4.y, dRr[q*4+1], rd1);
      rd0 = fmaf(h4.z, dRr[q*4+2], rd0); rd1 = fmaf(h4.w, dRr[q*4+3], rd1);
    }
    float p = p0 + p1;
    p += __shfl_xor(p, 1); p += __shfl_xor(p, 2);
    float E = __expf(2.0f*(p + adb_u));
    if (g4 == 0) s_hs[u4] = E;
    __syncthreads();  // b1

    // C: t'=u4, u-slice g4*16..+16
    float sA = 0.f, sB = 0.f;
#pragma unroll
    for (int q = 0; q < 4; ++q) {
      float4 Ev = *(const float4*)&s_hs[g4*16 + q*4];
      sA = fmaf(advr[q*4+0], rcpf_(fmaf(Ev.x, pd_[q*4+0], 1.f)), sA);
      sB = fmaf(advr[q*4+1], rcpf_(fmaf(Ev.y, pd_[q*4+1], 1.f)), sB);
      sA = fmaf(advr[q*4+2], rcpf_(fmaf(Ev.z, pd_[q*4+2], 1.f)), sA);
      sB = fmaf(advr[q*4+3], rcpf_(fmaf(Ev.w, pd_[q*4+3], 1.f)), sB);
    }
    float sacc = sA + sB;
    sacc += __shfl_xor(sacc, 1); sacc += __shfl_xor(sacc, 2);
    float sc = fmaf(-2.f, sacc, vsumd);
    float pe = __expf(sc);
    if (g4 == 0) s_pe[u4] = pe;
    float ws = pe;   // xor{4..32} sums the wave's 16 distinct t' once each
    ws += __shfl_xor(ws,4); ws += __shfl_xor(ws,8);
    ws += __shfl_xor(ws,16); ws += __shfl_xor(ws,32);
    if (lane == 0) s_redB[wv] = ws;
    __syncthreads();  // b2

    // z[k] = invS*(pe.XMr) + rd + y*m2k + mbk
    float4 r = *(const float4*)&s_redB[0];
    float invS = rcpf_((r.x + r.y) + (r.z + r.w));
    float q0 = 0.f, q1 = 0.f;
#pragma unroll
    for (int q = 0; q < 16; ++q) {
      float4 pv = *(const float4*)&s_pe[q*4];
      q0 = fmaf(pv.x, XMr[q*4+0], q0); q1 = fmaf(pv.y, XMr[q*4+1], q1);
      q0 = fmaf(pv.z, XMr[q*4+2], q0); q1 = fmaf(pv.w, XMr[q*4+3], q1);
    }
    float v = fmaf(q0+q1, invS, fmaf(s_yprev[t], m2k, (rd0+rd1) + mbk));
    float a = (wv == 2) ? tanh_e(v) : sigm(v);
    s_ag[tid] = a;
    __syncthreads();  // b3

    if (tid < 64) {
      float gi = s_ag[tid], gf = s_ag[64+tid], gg = s_ag[128+tid], go = s_ag[192+tid];
      float cn = fmaf(gf, s_c[tid], gi*gg);
      s_c[tid] = cn;
      s_h[tid] = go * tanh_e(cn);
    }
    __syncthreads();  // b4
  }

  // final context from last step's pe/S
  {
    float4 r = *(const float4*)&s_redB[0];
    float invS = rcpf_((r.x + r.y) + (r.z + r.w));
    float pc = 0.f;
#pragma unroll
    for (int q = 0; q < 16; ++q)
      pc = fmaf(s_pe[g4*16 + q], s_xenc[(g4*16 + q)*68 + u4], pc);
    pc += __shfl_xor(pc, 1); pc += __shfl_xor(pc, 2);
    if (g4 == 0) s_ctx[u4] = pc * invS;
  }
  __syncthreads();

  // epilogue: out = [d_n, ctx] @ fcfW + fcfb
  {
    float a0 = fcfb[tid], a1 = 0.f, a2 = 0.f, a3 = 0.f;
#pragma unroll
    for (int q = 0; q < 16; ++q) {
      float4 h4 = *(const float4*)&s_h[q*4];
      a0 = fmaf(h4.x, fcfW[(q*4+0)*256 + tid], a0);
      a1 = fmaf(h4.y, fcfW[(q*4+1)*256 + tid], a1);
      a2 = fmaf(h4.z, fcfW[(q*4+2)*256 + tid], a2);
      a3 = fmaf(h4.w, fcfW[(q*4+3)*256 + tid], a3);
      float4 c4 = *(const float4*)&s_ctx[q*4];
      a0 = fmaf(c4.x, fcfW[(64 + q*4+0)*256 + tid], a0);
      a1 = fmaf(c4.y, fcfW[(64 + q*4+1)*256 + tid], a1);
      a2 = fmaf(c4.z, fcfW[(64 + q*4+2)*256 + tid], a2);
      a3 = fmaf(c4.w, fcfW[(64 + q*4+3)*256 + tid], a3);
    }
    out[b*256 + tid] = (a0 + a1) + (a2 + a3);
  }
}

extern "C" void kernel_launch(void* const* d_in, const int* in_sizes, int n_in,
                              void* d_out, int out_size, void* d_ws, size_t ws_size,
                              hipStream_t stream) {
  const float* gin  = (const float*)d_in[0];
  const float* eK   = (const float*)d_in[1];
  const float* eR   = (const float*)d_in[2];
  const float* eb   = (const float*)d_in[3];
  const float* dK   = (const float*)d_in[4];
  const float* dR   = (const float*)d_in[5];
  const float* db   = (const float*)d_in[6];
  const float* aeW  = (const float*)d_in[7];
  const float* aeb  = (const float*)d_in[8];
  const float* aev  = (const float*)d_in[9];
  // d_in[10] attn_e_vb, d_in[14] attn_d_vb: constant shifts, cancel in softmax
  const float* adW  = (const float*)d_in[11];
  const float* adb  = (const float*)d_in[12];
  const float* adv  = (const float*)d_in[13];
  const float* fcW  = (const float*)d_in[15];
  const float* fcb  = (const float*)d_in[16];
  const float* fcfW = (const float*)d_in[17];
  const float* fcfb = (const float*)d_in[18];
  float* out = (float*)d_out;

  const int B = in_sizes[0] / (64*256);
  hipLaunchKernelGGL(darnn_fused, dim3(B), dim3(256), 0, stream,
                     gin, eK, eR, eb, dK, dR, db, aeW, aeb, aev,
                     adW, adb, adv, fcW, fcb, fcfW, fcfb, out);
}